// Round 12
// baseline (74.585 us; speedup 1.0000x reference)
//
#include <hip/hip_runtime.h>

static constexpr int D = 128;
static constexpr int BSH = 9;          // nodes per bucket = 512
static constexpr int BSZ = 1 << BSH;   // 512
static constexpr int MAXB = 128;       // max buckets (requires N <= 65536)
static constexpr int CAP = 10240;      // edge slots per bucket (mean 8163,
                                       // sigma ~90 for E=800k/N=50k -> 20+sigma)
static constexpr int FCH = CAP / 1024; // bfill edges per thread (10)

typedef __attribute__((ext_vector_type(8))) short bf16x8;
typedef __attribute__((ext_vector_type(4))) float f32x4;

// ---------------------------------------------------------------------------
// Pack two fp32 into two bf16 (RNE), elem0 -> low 16, elem1 -> high 16.
// ---------------------------------------------------------------------------
__device__ inline unsigned bf16pk(float a, float b) {
  unsigned ua = __float_as_uint(a), ub = __float_as_uint(b);
  ua = (ua + 0x7fffu + ((ua >> 16) & 1u)) >> 16;
  ub = (ub + 0x7fffu + ((ub >> 16) & 1u)) & 0xffff0000u;
  return ua | ub;
}

__device__ inline void acc8(float* acc, uint4 u) {
  acc[0] += __uint_as_float(u.x << 16);
  acc[1] += __uint_as_float(u.x & 0xffff0000u);
  acc[2] += __uint_as_float(u.y << 16);
  acc[3] += __uint_as_float(u.y & 0xffff0000u);
  acc[4] += __uint_as_float(u.z << 16);
  acc[5] += __uint_as_float(u.z & 0xffff0000u);
  acc[6] += __uint_as_float(u.w << 16);
  acc[7] += __uint_as_float(u.w & 0xffff0000u);
}

// ---------------------------------------------------------------------------
// Convert x (fp32) -> xh (bf16), 8 elems/thread. Block 0 zeroes bcur (stream
// order puts this dispatch before gnn_bpart's atomics).
// ---------------------------------------------------------------------------
__global__ __launch_bounds__(256) void gnn_cvt(const float* __restrict__ x,
                                               unsigned* __restrict__ xh,
                                               int total16,
                                               int* __restrict__ bcur) {
  if (blockIdx.x == 0 && threadIdx.x < MAXB) bcur[threadIdx.x] = 0;
  int i = blockIdx.x * 256 + threadIdx.x;
  if (i >= total16) return;
  const float4* x4 = reinterpret_cast<const float4*>(x);
  float4 a = x4[2 * i], b = x4[2 * i + 1];
  uint4 o;
  o.x = bf16pk(a.x, a.y);
  o.y = bf16pk(a.z, a.w);
  o.z = bf16pk(b.x, b.y);
  o.w = bf16pk(b.z, b.w);
  reinterpret_cast<uint4*>(xh)[i] = o;
}

// ---------------------------------------------------------------------------
// Partition edges into fixed-capacity bucket slices of ebuf (packed entry
// (dst&511)<<16 | src; requires N <= 65536). Each block reserves a run in
// bucket b at b*CAP + atomicAdd(bcur[b], cnt[b]).
// ---------------------------------------------------------------------------
__global__ __launch_bounds__(256) void gnn_bpart(const int* __restrict__ ei,
                                                 int* __restrict__ bcur,
                                                 unsigned* __restrict__ ebuf,
                                                 int E) {
  __shared__ int cnt[MAXB];
  __shared__ int gbase[MAXB];
  const int tid = threadIdx.x;
  if (tid < MAXB) cnt[tid] = 0;
  __syncthreads();
  const int base = blockIdx.x * 4096;
  int sv[16], dv[16], rk[16];
#pragma unroll
  for (int i = 0; i < 16; ++i) {
    int e = base + i * 256 + tid;
    rk[i] = -1;
    if (e < E) {
      sv[i] = ei[e];
      dv[i] = ei[E + e];
      rk[i] = atomicAdd(&cnt[dv[i] >> BSH], 1);
    }
  }
  __syncthreads();
  if (tid < MAXB && cnt[tid])
    gbase[tid] = tid * CAP + atomicAdd(&bcur[tid], cnt[tid]);
  __syncthreads();
#pragma unroll
  for (int i = 0; i < 16; ++i) {
    if (rk[i] >= 0) {
      int b = dv[i] >> BSH;
      ebuf[gbase[b] + rk[i]] =
          ((unsigned)(dv[i] & (BSZ - 1)) << 16) | (unsigned)sv[i];
    }
  }
}

// ---------------------------------------------------------------------------
// Per-bucket CSR finalize, SINGLE PASS over ebuf: stage edges + ranks in
// registers (LDS-atomic ranking), LDS scan of the 512 node counts, then
// scatter esrc from registers with NO atomics. seg[j] = {start, end} in the
// padded esrc space (slot base = bid*CAP).
// ---------------------------------------------------------------------------
__global__ __launch_bounds__(1024) void gnn_bfill(
    const unsigned* __restrict__ ebuf, const int* __restrict__ bcur,
    int2* __restrict__ seg, int* __restrict__ esrc, int N) {
  __shared__ int cnt[BSZ];
  const int tid = threadIdx.x;
  const int bid = blockIdx.x;
  const int bnode = bid << BSH;
  const int ebeg = bid * CAP;
  const int ne = bcur[bid];
  if (tid < BSZ) cnt[tid] = 0;
  __syncthreads();

  unsigned uv[FCH];
  int rk[FCH];
#pragma unroll
  for (int c = 0; c < FCH; ++c) {
    int k = tid + c * 1024;
    rk[c] = -1;
    if (k < ne) {
      uv[c] = ebuf[ebeg + k];
      rk[c] = atomicAdd(&cnt[uv[c] >> 16], 1);
    }
  }
  __syncthreads();
  int v = (tid < BSZ) ? cnt[tid] : 0;
  for (int off = 1; off < BSZ; off <<= 1) {
    int t = (tid >= off && tid < BSZ) ? cnt[tid - off] : 0;
    __syncthreads();
    if (tid < BSZ) cnt[tid] += t;
    __syncthreads();
  }
  int gslot = 0;
  if (tid < BSZ) {
    gslot = ebeg + cnt[tid] - v;  // segment start for this node
    if (bnode + tid < N) seg[bnode + tid] = make_int2(gslot, gslot + v);
  }
  __syncthreads();
  if (tid < BSZ) cnt[tid] = gslot;  // cnt[node] = segment start
  __syncthreads();
#pragma unroll
  for (int c = 0; c < FCH; ++c) {
    if (rk[c] >= 0)
      esrc[cnt[uv[c] >> 16] + rk[c]] = (int)(uv[c] & 0xffffu);
  }
}

// ---------------------------------------------------------------------------
// Gather: aggh[j] = bf16(xh[j] + sum xh[esrc[e]]), fp32 accumulate.
// 16 lanes/node, uint4 per lane; edge loop unrolled x8 (+x4 +scalar tails)
// so each lane keeps up to 8 independent 16B loads in flight (MLP).
// ---------------------------------------------------------------------------
__global__ __launch_bounds__(256) void gnn_gather(
    const unsigned* __restrict__ xh, const int2* __restrict__ seg,
    const int* __restrict__ esrc, unsigned* __restrict__ aggh, int N) {
  int j = blockIdx.x * 16 + (threadIdx.x >> 4);
  if (j >= N) return;
  const int c = threadIdx.x & 15;
  const uint4* xh4 = reinterpret_cast<const uint4*>(xh);

  float acc[8];
  {
    uint4 u = xh4[(size_t)j * 16 + c];  // self loop
    acc[0] = __uint_as_float(u.x << 16);
    acc[1] = __uint_as_float(u.x & 0xffff0000u);
    acc[2] = __uint_as_float(u.y << 16);
    acc[3] = __uint_as_float(u.y & 0xffff0000u);
    acc[4] = __uint_as_float(u.z << 16);
    acc[5] = __uint_as_float(u.z & 0xffff0000u);
    acc[6] = __uint_as_float(u.w << 16);
    acc[7] = __uint_as_float(u.w & 0xffff0000u);
  }
  const int2 sg = seg[j];
  const int en = sg.y;
  int e = sg.x;
  for (; e + 8 <= en; e += 8) {
    uint4 u0 = xh4[(size_t)esrc[e + 0] * 16 + c];
    uint4 u1 = xh4[(size_t)esrc[e + 1] * 16 + c];
    uint4 u2 = xh4[(size_t)esrc[e + 2] * 16 + c];
    uint4 u3 = xh4[(size_t)esrc[e + 3] * 16 + c];
    uint4 u4 = xh4[(size_t)esrc[e + 4] * 16 + c];
    uint4 u5 = xh4[(size_t)esrc[e + 5] * 16 + c];
    uint4 u6 = xh4[(size_t)esrc[e + 6] * 16 + c];
    uint4 u7 = xh4[(size_t)esrc[e + 7] * 16 + c];
    acc8(acc, u0);
    acc8(acc, u1);
    acc8(acc, u2);
    acc8(acc, u3);
    acc8(acc, u4);
    acc8(acc, u5);
    acc8(acc, u6);
    acc8(acc, u7);
  }
  if (e + 4 <= en) {
    uint4 u0 = xh4[(size_t)esrc[e + 0] * 16 + c];
    uint4 u1 = xh4[(size_t)esrc[e + 1] * 16 + c];
    uint4 u2 = xh4[(size_t)esrc[e + 2] * 16 + c];
    uint4 u3 = xh4[(size_t)esrc[e + 3] * 16 + c];
    acc8(acc, u0);
    acc8(acc, u1);
    acc8(acc, u2);
    acc8(acc, u3);
    e += 4;
  }
  for (; e < en; ++e) {
    uint4 u = xh4[(size_t)esrc[e] * 16 + c];
    acc8(acc, u);
  }
  uint4 pk;
  pk.x = bf16pk(acc[0], acc[1]);
  pk.y = bf16pk(acc[2], acc[3]);
  pk.z = bf16pk(acc[4], acc[5]);
  pk.w = bf16pk(acc[6], acc[7]);
  *reinterpret_cast<uint4*>(aggh + (size_t)j * 64 + c * 4) = pk;
}

// ---------------------------------------------------------------------------
// MFMA GEMM: out[i][o] = sum_k aggh[i][k] * bf16(W[o][k]). Block = 128 rows,
// 4 waves; wave owns 32 rows (2 m-tiles x 8 o-tiles, mfma_f32_16x16x32_bf16).
// A frags load directly as bf16x8. W staged fp32->bf16 in padded LDS
// [128][136]. A/B use the SAME (lg,kb)->k mapping (HW k-permutation cancels);
// C/D store col=lane&15, row=(lane>>4)*4+reg (verified layout).
// ---------------------------------------------------------------------------
__global__ __launch_bounds__(256) void gnn_gemm_mfma(
    const unsigned* __restrict__ aggh, const float* __restrict__ W,
    float* __restrict__ out, int N) {
  __shared__ short Wh[D][136];  // row stride 272 B
  const int tid = threadIdx.x;

  {
    const float4* W4 = reinterpret_cast<const float4*>(W);
    for (int q = tid; q < D * D / 4; q += 256) {
      int o = q >> 5, kq = q & 31;
      float4 w = W4[q];
      uint2 p;
      p.x = bf16pk(w.x, w.y);
      p.y = bf16pk(w.z, w.w);
      *reinterpret_cast<uint2*>(&Wh[o][kq * 4]) = p;
    }
  }
  __syncthreads();

  const int wid = tid >> 6;
  const int l = tid & 63;
  const int lr = l & 15;  // A row-in-tile / B col / D col
  const int lg = l >> 4;  // k-group / D row-group
  const long rowbase = (long)blockIdx.x * 128 + wid * 32;

  bf16x8 a[2][4];
#pragma unroll
  for (int m = 0; m < 2; ++m) {
    long row = rowbase + m * 16 + lr;
    if (row >= N) row = N - 1;
#pragma unroll
    for (int kb = 0; kb < 4; ++kb)
      a[m][kb] = *reinterpret_cast<const bf16x8*>(aggh + row * 64 + kb * 16 +
                                                  lg * 4);
  }

  f32x4 acc[2][8];
#pragma unroll
  for (int m = 0; m < 2; ++m)
#pragma unroll
    for (int ot = 0; ot < 8; ++ot) acc[m][ot] = (f32x4){0.f, 0.f, 0.f, 0.f};

#pragma unroll
  for (int ot = 0; ot < 8; ++ot) {
    bf16x8 b[4];
#pragma unroll
    for (int kb = 0; kb < 4; ++kb)
      b[kb] =
          *reinterpret_cast<const bf16x8*>(&Wh[ot * 16 + lr][kb * 32 + lg * 8]);
#pragma unroll
    for (int m = 0; m < 2; ++m)
#pragma unroll
      for (int kb = 0; kb < 4; ++kb)
        acc[m][ot] = __builtin_amdgcn_mfma_f32_16x16x32_bf16(a[m][kb], b[kb],
                                                             acc[m][ot], 0, 0, 0);
  }

#pragma unroll
  for (int m = 0; m < 2; ++m) {
#pragma unroll
    for (int r = 0; r < 4; ++r) {
      long row = rowbase + m * 16 + lg * 4 + r;
      if (row >= N) continue;
#pragma unroll
      for (int ot = 0; ot < 8; ++ot)
        out[row * D + ot * 16 + lr] = acc[m][ot][r];
    }
  }
}

extern "C" void kernel_launch(void* const* d_in, const int* in_sizes, int n_in,
                              void* d_out, int out_size, void* d_ws,
                              size_t ws_size, hipStream_t stream) {
  const float* x = (const float*)d_in[0];
  const int* ei = (const int*)d_in[1];  // [2, E]: first E = src, next E = dst
  const float* W = (const float*)d_in[2];
  float* out = (float*)d_out;

  const int N = in_sizes[0] / D;
  const int E = in_sizes[1] / 2;
  const int nbuck = (N + BSZ - 1) >> BSH;  // 98 for N=50000 (<= MAXB)

  // Workspace (uints): xh[N*64] | aggh[N*64] | ebuf[nbuck*CAP] |
  //                    esrc[nbuck*CAP] | seg[N] (int2) | bcur[MAXB]
  unsigned* xh = (unsigned*)d_ws;
  unsigned* aggh = xh + (size_t)N * 64;
  unsigned* ebuf = aggh + (size_t)N * 64;
  int* esrc = (int*)(ebuf + (size_t)nbuck * CAP);
  int2* seg = (int2*)(esrc + (size_t)nbuck * CAP);
  int* bcur = (int*)(seg + N);

  const int nbp = (E + 4095) / 4096;

  gnn_cvt<<<(N * 16 + 255) / 256, 256, 0, stream>>>(x, xh, N * 16, bcur);
  gnn_bpart<<<nbp, 256, 0, stream>>>(ei, bcur, ebuf, E);
  gnn_bfill<<<nbuck, 1024, 0, stream>>>(ebuf, bcur, seg, esrc, N);
  gnn_gather<<<(N + 15) / 16, 256, 0, stream>>>(xh, seg, esrc, aggh, N);
  gnn_gemm_mfma<<<(N + 127) / 128, 256, 0, stream>>>(aggh, W, out, N);
}

// Round 13
// 72.444 us; speedup vs baseline: 1.0296x; 1.0296x over previous
//
#include <hip/hip_runtime.h>

static constexpr int D = 128;
static constexpr int BSH = 9;          // nodes per bucket = 512
static constexpr int BSZ = 1 << BSH;   // 512
static constexpr int MAXB = 128;       // max buckets (requires N <= 65536)
static constexpr int CAP = 10240;      // edge slots per bucket (mean 8163,
                                       // sigma ~90 for E=800k/N=50k -> 20+sigma)

typedef __attribute__((ext_vector_type(8))) short bf16x8;
typedef __attribute__((ext_vector_type(4))) float f32x4;

// ---------------------------------------------------------------------------
// Pack two fp32 into two bf16 (RNE), elem0 -> low 16, elem1 -> high 16.
// ---------------------------------------------------------------------------
__device__ inline unsigned bf16pk(float a, float b) {
  unsigned ua = __float_as_uint(a), ub = __float_as_uint(b);
  ua = (ua + 0x7fffu + ((ua >> 16) & 1u)) >> 16;
  ub = (ub + 0x7fffu + ((ub >> 16) & 1u)) & 0xffff0000u;
  return ua | ub;
}

__device__ inline void acc8(float* acc, uint4 u) {
  acc[0] += __uint_as_float(u.x << 16);
  acc[1] += __uint_as_float(u.x & 0xffff0000u);
  acc[2] += __uint_as_float(u.y << 16);
  acc[3] += __uint_as_float(u.y & 0xffff0000u);
  acc[4] += __uint_as_float(u.z << 16);
  acc[5] += __uint_as_float(u.z & 0xffff0000u);
  acc[6] += __uint_as_float(u.w << 16);
  acc[7] += __uint_as_float(u.w & 0xffff0000u);
}

// ---------------------------------------------------------------------------
// Convert x (fp32) -> xh (bf16), 8 elems/thread. Block 0 zeroes bcur (stream
// order puts this dispatch before gnn_bpart's atomics).
// ---------------------------------------------------------------------------
__global__ __launch_bounds__(256) void gnn_cvt(const float* __restrict__ x,
                                               unsigned* __restrict__ xh,
                                               int total16,
                                               int* __restrict__ bcur) {
  if (blockIdx.x == 0 && threadIdx.x < MAXB) bcur[threadIdx.x] = 0;
  int i = blockIdx.x * 256 + threadIdx.x;
  if (i >= total16) return;
  const float4* x4 = reinterpret_cast<const float4*>(x);
  float4 a = x4[2 * i], b = x4[2 * i + 1];
  uint4 o;
  o.x = bf16pk(a.x, a.y);
  o.y = bf16pk(a.z, a.w);
  o.z = bf16pk(b.x, b.y);
  o.w = bf16pk(b.z, b.w);
  reinterpret_cast<uint4*>(xh)[i] = o;
}

// ---------------------------------------------------------------------------
// Partition edges into fixed-capacity bucket slices of ebuf (packed entry
// (dst&511)<<16 | src; requires N <= 65536). Each block reserves a run in
// bucket b at b*CAP + atomicAdd(bcur[b], cnt[b]).
// ---------------------------------------------------------------------------
__global__ __launch_bounds__(256) void gnn_bpart(const int* __restrict__ ei,
                                                 int* __restrict__ bcur,
                                                 unsigned* __restrict__ ebuf,
                                                 int E) {
  __shared__ int cnt[MAXB];
  __shared__ int gbase[MAXB];
  const int tid = threadIdx.x;
  if (tid < MAXB) cnt[tid] = 0;
  __syncthreads();
  const int base = blockIdx.x * 4096;
  int sv[16], dv[16], rk[16];
#pragma unroll
  for (int i = 0; i < 16; ++i) {
    int e = base + i * 256 + tid;
    rk[i] = -1;
    if (e < E) {
      sv[i] = ei[e];
      dv[i] = ei[E + e];
      rk[i] = atomicAdd(&cnt[dv[i] >> BSH], 1);
    }
  }
  __syncthreads();
  if (tid < MAXB && cnt[tid])
    gbase[tid] = tid * CAP + atomicAdd(&bcur[tid], cnt[tid]);
  __syncthreads();
#pragma unroll
  for (int i = 0; i < 16; ++i) {
    if (rk[i] >= 0) {
      int b = dv[i] >> BSH;
      ebuf[gbase[b] + rk[i]] =
          ((unsigned)(dv[i] & (BSZ - 1)) << 16) | (unsigned)sv[i];
    }
  }
}

// ---------------------------------------------------------------------------
// Per-bucket CSR finalize with SRC-TILE ordering. Rank key =
// (locnode<<2) | tile, tile = src*5>>16 (4 tiles of ~13k nodes = 3.3MB bf16,
// L2-resident). Within each node's segment, edges end up grouped by src tile
// -> all concurrent gather waves walk tiles in the same order -> per-XCD L2
// holds the active tile. Segment sums are order-independent (numerics
// unchanged). seg[j] = {start of key 4j, inclusive end of key 4j+3}.
// ---------------------------------------------------------------------------
__global__ __launch_bounds__(1024) void gnn_bfill(
    const unsigned* __restrict__ ebuf, const int* __restrict__ bcur,
    int* __restrict__ segi, int* __restrict__ esrc, int N) {
  __shared__ int cnt[2 * 1024];  // 2048 keys: (locnode<<2)|tile
  __shared__ int sc[1024];
  const int tid = threadIdx.x;
  const int bid = blockIdx.x;
  const int bnode = bid << BSH;
  const int ebeg = bid * CAP;
  const int ne = bcur[bid];
  cnt[tid] = 0;
  cnt[tid + 1024] = 0;
  __syncthreads();
  for (int k = tid; k < ne; k += 1024) {
    unsigned u = ebuf[ebeg + k];
    unsigned src = u & 0xffffu;
    atomicAdd(&cnt[((u >> 16) << 2) | ((src * 5u) >> 16)], 1);
  }
  __syncthreads();
  // Pairwise scan: thread t owns keys 2t, 2t+1.
  int c0 = cnt[2 * tid], c1 = cnt[2 * tid + 1];
  sc[tid] = c0 + c1;
  __syncthreads();
  for (int off = 1; off < 1024; off <<= 1) {
    int t = (tid >= off) ? sc[tid - off] : 0;
    __syncthreads();
    sc[tid] += t;
    __syncthreads();
  }
  const int base = (tid > 0) ? sc[tid - 1] : 0;  // exclusive over pairs
  const int s0 = base, s1 = base + c0;           // exclusive starts of 2t,2t+1
  {
    // Node j spans keys 4j..4j+3: thread 2j holds its start (key 4j);
    // thread 2j+1 holds its inclusive end (key 4j+3).
    int gn = bnode + (tid >> 1);
    if (gn < N) {
      if ((tid & 1) == 0)
        segi[2 * gn] = ebeg + s0;                // segment start
      else
        segi[2 * gn + 1] = ebeg + base + c0 + c1;  // segment end
    }
  }
  cnt[2 * tid] = ebeg + s0;  // cursors
  cnt[2 * tid + 1] = ebeg + s1;
  __syncthreads();
  for (int k = tid; k < ne; k += 1024) {
    unsigned u = ebuf[ebeg + k];
    unsigned src = u & 0xffffu;
    int key = ((u >> 16) << 2) | ((src * 5u) >> 16);
    int slot = atomicAdd(&cnt[key], 1);
    esrc[slot] = (int)src;
  }
}

// ---------------------------------------------------------------------------
// Gather: aggh[j] = bf16(xh[j] + sum xh[esrc[e]]), fp32 accumulate.
// 16 lanes/node, uint4 per lane; edge loop unrolled x4 (R11-proven form).
// ---------------------------------------------------------------------------
__global__ __launch_bounds__(256) void gnn_gather(
    const unsigned* __restrict__ xh, const int2* __restrict__ seg,
    const int* __restrict__ esrc, unsigned* __restrict__ aggh, int N) {
  int j = blockIdx.x * 16 + (threadIdx.x >> 4);
  if (j >= N) return;
  const int c = threadIdx.x & 15;
  const uint4* xh4 = reinterpret_cast<const uint4*>(xh);

  float acc[8];
  {
    uint4 u = xh4[(size_t)j * 16 + c];  // self loop
    acc[0] = __uint_as_float(u.x << 16);
    acc[1] = __uint_as_float(u.x & 0xffff0000u);
    acc[2] = __uint_as_float(u.y << 16);
    acc[3] = __uint_as_float(u.y & 0xffff0000u);
    acc[4] = __uint_as_float(u.z << 16);
    acc[5] = __uint_as_float(u.z & 0xffff0000u);
    acc[6] = __uint_as_float(u.w << 16);
    acc[7] = __uint_as_float(u.w & 0xffff0000u);
  }
  const int2 sg = seg[j];
  const int en = sg.y;
  int e = sg.x;
  for (; e + 4 <= en; e += 4) {
    int s0 = esrc[e + 0], s1 = esrc[e + 1], s2 = esrc[e + 2], s3 = esrc[e + 3];
    uint4 u0 = xh4[(size_t)s0 * 16 + c];
    uint4 u1 = xh4[(size_t)s1 * 16 + c];
    uint4 u2 = xh4[(size_t)s2 * 16 + c];
    uint4 u3 = xh4[(size_t)s3 * 16 + c];
    acc8(acc, u0);
    acc8(acc, u1);
    acc8(acc, u2);
    acc8(acc, u3);
  }
  for (; e < en; ++e) {
    uint4 u = xh4[(size_t)esrc[e] * 16 + c];
    acc8(acc, u);
  }
  uint4 pk;
  pk.x = bf16pk(acc[0], acc[1]);
  pk.y = bf16pk(acc[2], acc[3]);
  pk.z = bf16pk(acc[4], acc[5]);
  pk.w = bf16pk(acc[6], acc[7]);
  *reinterpret_cast<uint4*>(aggh + (size_t)j * 64 + c * 4) = pk;
}

// ---------------------------------------------------------------------------
// MFMA GEMM: out[i][o] = sum_k aggh[i][k] * bf16(W[o][k]). Block = 128 rows,
// 4 waves; wave owns 32 rows (2 m-tiles x 8 o-tiles, mfma_f32_16x16x32_bf16).
// A frags load directly as bf16x8. W staged fp32->bf16 in padded LDS
// [128][136]. A/B use the SAME (lg,kb)->k mapping (HW k-permutation cancels);
// C/D store col=lane&15, row=(lane>>4)*4+reg (verified layout).
// ---------------------------------------------------------------------------
__global__ __launch_bounds__(256) void gnn_gemm_mfma(
    const unsigned* __restrict__ aggh, const float* __restrict__ W,
    float* __restrict__ out, int N) {
  __shared__ short Wh[D][136];  // row stride 272 B
  const int tid = threadIdx.x;

  {
    const float4* W4 = reinterpret_cast<const float4*>(W);
    for (int q = tid; q < D * D / 4; q += 256) {
      int o = q >> 5, kq = q & 31;
      float4 w = W4[q];
      uint2 p;
      p.x = bf16pk(w.x, w.y);
      p.y = bf16pk(w.z, w.w);
      *reinterpret_cast<uint2*>(&Wh[o][kq * 4]) = p;
    }
  }
  __syncthreads();

  const int wid = tid >> 6;
  const int l = tid & 63;
  const int lr = l & 15;  // A row-in-tile / B col / D col
  const int lg = l >> 4;  // k-group / D row-group
  const long rowbase = (long)blockIdx.x * 128 + wid * 32;

  bf16x8 a[2][4];
#pragma unroll
  for (int m = 0; m < 2; ++m) {
    long row = rowbase + m * 16 + lr;
    if (row >= N) row = N - 1;
#pragma unroll
    for (int kb = 0; kb < 4; ++kb)
      a[m][kb] = *reinterpret_cast<const bf16x8*>(aggh + row * 64 + kb * 16 +
                                                  lg * 4);
  }

  f32x4 acc[2][8];
#pragma unroll
  for (int m = 0; m < 2; ++m)
#pragma unroll
    for (int ot = 0; ot < 8; ++ot) acc[m][ot] = (f32x4){0.f, 0.f, 0.f, 0.f};

#pragma unroll
  for (int ot = 0; ot < 8; ++ot) {
    bf16x8 b[4];
#pragma unroll
    for (int kb = 0; kb < 4; ++kb)
      b[kb] =
          *reinterpret_cast<const bf16x8*>(&Wh[ot * 16 + lr][kb * 32 + lg * 8]);
#pragma unroll
    for (int m = 0; m < 2; ++m)
#pragma unroll
      for (int kb = 0; kb < 4; ++kb)
        acc[m][ot] = __builtin_amdgcn_mfma_f32_16x16x32_bf16(a[m][kb], b[kb],
                                                             acc[m][ot], 0, 0, 0);
  }

#pragma unroll
  for (int m = 0; m < 2; ++m) {
#pragma unroll
    for (int r = 0; r < 4; ++r) {
      long row = rowbase + m * 16 + lg * 4 + r;
      if (row >= N) continue;
#pragma unroll
      for (int ot = 0; ot < 8; ++ot)
        out[row * D + ot * 16 + lr] = acc[m][ot][r];
    }
  }
}

extern "C" void kernel_launch(void* const* d_in, const int* in_sizes, int n_in,
                              void* d_out, int out_size, void* d_ws,
                              size_t ws_size, hipStream_t stream) {
  const float* x = (const float*)d_in[0];
  const int* ei = (const int*)d_in[1];  // [2, E]: first E = src, next E = dst
  const float* W = (const float*)d_in[2];
  float* out = (float*)d_out;

  const int N = in_sizes[0] / D;
  const int E = in_sizes[1] / 2;
  const int nbuck = (N + BSZ - 1) >> BSH;  // 98 for N=50000 (<= MAXB)

  // Workspace (uints): xh[N*64] | aggh[N*64] | ebuf[nbuck*CAP] |
  //                    esrc[nbuck*CAP] | seg[N] (int2) | bcur[MAXB]
  unsigned* xh = (unsigned*)d_ws;
  unsigned* aggh = xh + (size_t)N * 64;
  unsigned* ebuf = aggh + (size_t)N * 64;
  int* esrc = (int*)(ebuf + (size_t)nbuck * CAP);
  int2* seg = (int2*)(esrc + (size_t)nbuck * CAP);
  int* bcur = (int*)(seg + N);

  const int nbp = (E + 4095) / 4096;

  gnn_cvt<<<(N * 16 + 255) / 256, 256, 0, stream>>>(x, xh, N * 16, bcur);
  gnn_bpart<<<nbp, 256, 0, stream>>>(ei, bcur, ebuf, E);
  gnn_bfill<<<nbuck, 1024, 0, stream>>>(ebuf, bcur, (int*)seg, esrc, N);
  gnn_gather<<<(N + 15) / 16, 256, 0, stream>>>(xh, seg, esrc, aggh, N);
  gnn_gemm_mfma<<<(N + 127) / 128, 256, 0, stream>>>(aggh, W, out, N);
}